// Round 8
// baseline (428.720 us; speedup 1.0000x reference)
//
#include <hip/hip_runtime.h>

#define NS 7
#define NA 131072
#define AEVD 1008
#define KP1 1024
#define N1 256
#define N2 192
#define N3 160
#define GR 32          // atoms per group
#define APITCH 40      // A-chunk pitch (u16)
#define H1P 264
#define H2P 200
#define H3P 168

typedef __attribute__((ext_vector_type(8))) short short8;
typedef __attribute__((ext_vector_type(8))) unsigned short ushortx8;
typedef __attribute__((ext_vector_type(4))) float f32x4;
typedef __attribute__((ext_vector_type(4))) float fvec4;
typedef unsigned short u16;

// LDS-only barrier: ds ops drained, vmem register loads stay in flight.
#define BAR() asm volatile("s_waitcnt lgkmcnt(0)\ns_barrier" ::: "memory")

__device__ __forceinline__ u16 f2bf(float f) {
  unsigned u = __builtin_bit_cast(unsigned, f);
  u += 0x7fffu + ((u >> 16) & 1u);
  return (u16)(u >> 16);
}
__device__ __forceinline__ float bf2f(u16 h) {
  return __builtin_bit_cast(float, ((unsigned)h) << 16);
}
__device__ __forceinline__ float celu_f(float x) {
  return x > 0.f ? x : 0.1f * (__expf(x * 10.f) - 1.f);
}
__device__ __forceinline__ fvec4 ld_aev(const float* row, int k) {
  if (k + 4 <= AEVD) return *(const fvec4*)(row + k);
  fvec4 z = {0.f, 0.f, 0.f, 0.f};
  return z;
}

// ---------------- bucketing ----------------
__global__ void count_kernel(const int* __restrict__ species, int* __restrict__ counts) {
  __shared__ int h[NS];
  if (threadIdx.x < NS) h[threadIdx.x] = 0;
  __syncthreads();
  int i = blockIdx.x * blockDim.x + threadIdx.x;
  if (i < NA) atomicAdd(&h[species[i]], 1);
  __syncthreads();
  if (threadIdx.x < NS) atomicAdd(&counts[threadIdx.x], h[threadIdx.x]);
}

__global__ void scan_kernel(const int* __restrict__ counts, int* __restrict__ offsets,
                            int* __restrict__ cursors, int* __restrict__ gstart) {
  int off = 0, gs = 0;
  for (int e = 0; e < NS; ++e) {
    offsets[e] = off; cursors[e] = off; gstart[e] = gs;
    off += counts[e];
    gs += (counts[e] + GR - 1) / GR;
  }
  offsets[NS] = off; gstart[NS] = gs;
}

__global__ void scatter_kernel(const int* __restrict__ species, int* __restrict__ cursors,
                               int* __restrict__ idx) {
  __shared__ int h[NS], lb[NS];
  if (threadIdx.x < NS) h[threadIdx.x] = 0;
  __syncthreads();
  int i = blockIdx.x * blockDim.x + threadIdx.x;
  int s = species[i];
  int lpos = atomicAdd(&h[s], 1);
  __syncthreads();
  if (threadIdx.x < NS) lb[threadIdx.x] = atomicAdd(&cursors[threadIdx.x], h[threadIdx.x]);
  __syncthreads();
  idx[lb[s] + lpos] = i;
}

// ---------------- weight convert: dst[e][n][kp] = bf16(src[e][k][n]), zero pad ----------------
__global__ void convert_w(const float* __restrict__ src, u16* __restrict__ dst,
                          int K, int N, int KP) {
  long total = (long)NS * N * KP;
  for (long i = (long)blockIdx.x * blockDim.x + threadIdx.x; i < total;
       i += (long)gridDim.x * blockDim.x) {
    int kp = (int)(i % KP);
    long t2 = i / KP;
    int n = (int)(t2 % N);
    int e = (int)(t2 / N);
    float v = (kp < K) ? src[((long)e * K + kp) * N + n] : 0.f;
    dst[i] = f2bf(v);
  }
}

// ---------------- fused MLP: 32 atoms/block, 2 waves, 5 blocks/CU ----------------
__global__ __launch_bounds__(128, 2) void ani_fused(
    const int* __restrict__ idx, const int* __restrict__ counts,
    const int* __restrict__ offsets, const int* __restrict__ gstart,
    const float* __restrict__ aev,
    const u16* __restrict__ W1t, const float* __restrict__ b1,
    const u16* __restrict__ W2t, const float* __restrict__ b2,
    const u16* __restrict__ W3t, const float* __restrict__ b3,
    const u16* __restrict__ Wht, const float* __restrict__ bh,
    float* __restrict__ out) {
  // REG0: A double-buffer (2*32*40=2560 u16), later H2 (32*200=6400 u16)
  // REG1: H1 (32*264 u16), later H3 (32*168)
  __shared__ __align__(16) u16 REG0[GR * H2P];
  __shared__ __align__(16) u16 REG1[GR * H1P];
  u16* H1 = REG1;
  u16* H2 = REG0;
  u16* H3 = REG1;

  // bijective XCD-chunk swizzle over launched grid (T1, m204)
  int gd = gridDim.x;
  int b0 = blockIdx.x;
  int q = gd >> 3, r = gd & 7;
  int xcd = b0 & 7, ii = b0 >> 3;
  int bid = (xcd < r ? xcd * (q + 1) : r * (q + 1) + (xcd - r) * q) + ii;

  if (bid >= gstart[NS]) return;
  int e = 0;
#pragma unroll
  for (int s = 1; s < NS; ++s)
    if (bid >= gstart[s]) e = s;
  int t0 = bid - gstart[e];
  int base = offsets[e] + t0 * GR;
  int mcount = counts[e] - t0 * GR;
  if (mcount > GR) mcount = GR;

  int tid = threadIdx.x;
  int lane = tid & 63;
  int w = tid >> 6;       // wave 0..1
  int lr = lane & 15;
  int kg = lane >> 4;

  // A staging: row = tid>>2 (0..31), k-sub = (tid&3)*8
  int arow = tid >> 2;
  int koff = (tid & 3) << 3;
  int rrow = arow < mcount ? arow : mcount - 1;
  const float* aevRow = aev + (size_t)idx[base + rrow] * AEVD;

  const u16* Wb1 = W1t + ((size_t)e * N1 + (w * 128 + lr)) * KP1 + kg * 8;

  fvec4 Ar[3][2];
  short8 Br[2][8];

  auto loadA = [&](int c, fvec4 (&d)[2]) {
    int k = c * 32 + koff;
    d[0] = ld_aev(aevRow, k);
    d[1] = ld_aev(aevRow, k + 4);
  };
  auto packA = [&](fvec4 (&v)[2], int buf) {
    ushortx8 p;
    p[0] = f2bf(v[0].x); p[1] = f2bf(v[0].y); p[2] = f2bf(v[0].z); p[3] = f2bf(v[0].w);
    p[4] = f2bf(v[1].x); p[5] = f2bf(v[1].y); p[6] = f2bf(v[1].z); p[7] = f2bf(v[1].w);
    *(ushortx8*)&REG0[buf * GR * APITCH + arow * APITCH + koff] = p;
  };
  auto loadB1 = [&](int c, short8 (&d)[8]) {
#pragma unroll
    for (int ni = 0; ni < 8; ++ni)
      d[ni] = *(const short8*)(Wb1 + (size_t)ni * 16 * KP1 + c * 32);
  };

  f32x4 acc[2][8] = {};

  // prologue
  loadA(0, Ar[0]); loadA(1, Ar[1]); loadA(2, Ar[2]);
  loadB1(0, Br[0]); loadB1(1, Br[1]);
  packA(Ar[0], 0);
  BAR();

  // ---- layer 1: [32 x 1008] @ [1008 x 256], 32 steps of BK=32, fully unrolled ----
#pragma unroll
  for (int c = 0; c < 32; ++c) {
    if (c + 3 < 32) loadA(c + 3, Ar[(c + 3) % 3]);   // top-of-step issue (T14)
    short8 af0 = *(const short8*)&REG0[(c & 1) * GR * APITCH + lr * APITCH + kg * 8];
    short8 af1 = *(const short8*)&REG0[(c & 1) * GR * APITCH + (16 + lr) * APITCH + kg * 8];
    __builtin_amdgcn_s_setprio(1);
#pragma unroll
    for (int ni = 0; ni < 8; ++ni) {
      acc[0][ni] = __builtin_amdgcn_mfma_f32_16x16x32_bf16(af0, Br[c & 1][ni], acc[0][ni], 0, 0, 0);
      acc[1][ni] = __builtin_amdgcn_mfma_f32_16x16x32_bf16(af1, Br[c & 1][ni], acc[1][ni], 0, 0, 0);
    }
    __builtin_amdgcn_s_setprio(0);
    if (c + 1 < 32) packA(Ar[(c + 1) % 3], (c + 1) & 1);
    if (c + 2 < 32) loadB1(c + 2, Br[c & 1]);
    BAR();
  }

  // ---- layer 2 B-ring prefetch (hoisted above epilogue-1) ----
  const u16* Wb2 = W2t + ((size_t)e * N2 + (w * 96 + lr)) * N1 + kg * 8;
  auto loadB2 = [&](int ks, short8 (&d)[6]) {
#pragma unroll
    for (int ni = 0; ni < 6; ++ni)
      d[ni] = *(const short8*)(Wb2 + (size_t)ni * 16 * N1 + ks * 32);
  };
  short8 r2a[6], r2b[6];
  loadB2(0, r2a); loadB2(1, r2b);

  // epilogue 1 -> H1
#pragma unroll
  for (int ni = 0; ni < 8; ++ni) {
    int col = w * 128 + ni * 16 + lr;
    float bias = b1[e * N1 + col];
#pragma unroll
    for (int mi = 0; mi < 2; ++mi)
#pragma unroll
      for (int rr = 0; rr < 4; ++rr)
        H1[(mi * 16 + kg * 4 + rr) * H1P + col] = f2bf(celu_f(acc[mi][ni][rr] + bias));
  }
  BAR();

  // ---- layer 2: [32 x 256] @ [256 x 192], no barriers ----
  f32x4 acc2[2][6] = {};
  auto mm2 = [&](int ks, short8 (&b)[6]) {
    short8 a0 = *(const short8*)&H1[lr * H1P + ks * 32 + kg * 8];
    short8 a1 = *(const short8*)&H1[(16 + lr) * H1P + ks * 32 + kg * 8];
#pragma unroll
    for (int ni = 0; ni < 6; ++ni) {
      acc2[0][ni] = __builtin_amdgcn_mfma_f32_16x16x32_bf16(a0, b[ni], acc2[0][ni], 0, 0, 0);
      acc2[1][ni] = __builtin_amdgcn_mfma_f32_16x16x32_bf16(a1, b[ni], acc2[1][ni], 0, 0, 0);
    }
  };
  mm2(0, r2a); loadB2(2, r2a);
  mm2(1, r2b); loadB2(3, r2b);
  mm2(2, r2a); loadB2(4, r2a);
  mm2(3, r2b); loadB2(5, r2b);
  mm2(4, r2a); loadB2(6, r2a);
  mm2(5, r2b); loadB2(7, r2b);
  mm2(6, r2a);
  mm2(7, r2b);

  // ---- layer 3 B-ring prefetch (hoisted above epilogue-2) ----
  const u16* Wb3 = W3t + ((size_t)e * N3 + (w * 80 + lr)) * N2 + kg * 8;
  auto loadB3 = [&](int ks, short8 (&d)[5]) {
#pragma unroll
    for (int ni = 0; ni < 5; ++ni)
      d[ni] = *(const short8*)(Wb3 + (size_t)ni * 16 * N2 + ks * 32);
  };
  short8 r3a[5], r3b[5];
  loadB3(0, r3a); loadB3(1, r3b);

  // epilogue 2 -> H2 (REG0; A-bufs dead since last layer-1 BAR)
#pragma unroll
  for (int ni = 0; ni < 6; ++ni) {
    int col = w * 96 + ni * 16 + lr;
    float bias = b2[e * N2 + col];
#pragma unroll
    for (int mi = 0; mi < 2; ++mi)
#pragma unroll
      for (int rr = 0; rr < 4; ++rr)
        H2[(mi * 16 + kg * 4 + rr) * H2P + col] = f2bf(celu_f(acc2[mi][ni][rr] + bias));
  }
  BAR();

  // ---- layer 3: [32 x 192] @ [192 x 160], no barriers ----
  f32x4 acc3[2][5] = {};
  auto mm3 = [&](int ks, short8 (&b)[5]) {
    short8 a0 = *(const short8*)&H2[lr * H2P + ks * 32 + kg * 8];
    short8 a1 = *(const short8*)&H2[(16 + lr) * H2P + ks * 32 + kg * 8];
#pragma unroll
    for (int ni = 0; ni < 5; ++ni) {
      acc3[0][ni] = __builtin_amdgcn_mfma_f32_16x16x32_bf16(a0, b[ni], acc3[0][ni], 0, 0, 0);
      acc3[1][ni] = __builtin_amdgcn_mfma_f32_16x16x32_bf16(a1, b[ni], acc3[1][ni], 0, 0, 0);
    }
  };
  mm3(0, r3a); loadB3(2, r3a);
  mm3(1, r3b); loadB3(3, r3b);
  mm3(2, r3a); loadB3(4, r3a);
  mm3(3, r3b); loadB3(5, r3b);
  mm3(4, r3a);
  mm3(5, r3b);

  // ---- head weights prefetch (hoisted above epilogue-3) ----
  int hr_ = tid >> 2;
  int ho = (tid >> 1) & 1;
  int kh = tid & 1;
  const u16* wr = Wht + ((size_t)e * 2 + ho) * N3 + kh * 80;
  ushortx8 wvv[10];
#pragma unroll
  for (int c = 0; c < 10; ++c) wvv[c] = *(const ushortx8*)&wr[c * 8];

  // epilogue 3 -> H3 (REG1; h1 dead after layer-2's last read + BAR)
#pragma unroll
  for (int ni = 0; ni < 5; ++ni) {
    int col = w * 80 + ni * 16 + lr;
    float bias = b3[e * N3 + col];
#pragma unroll
    for (int mi = 0; mi < 2; ++mi)
#pragma unroll
      for (int rr = 0; rr < 4; ++rr)
        H3[(mi * 16 + kg * 4 + rr) * H3P + col] = f2bf(celu_f(acc3[mi][ni][rr] + bias));
  }
  BAR();

  // ---- head: [32 x 160] @ [160 x 2], split-K halves over thread pairs ----
  {
    float s = 0.f;
    const u16* hrow = &H3[hr_ * H3P + kh * 80];
#pragma unroll
    for (int c = 0; c < 10; ++c) {
      ushortx8 hv = *(const ushortx8*)&hrow[c * 8];
#pragma unroll
      for (int j = 0; j < 8; ++j) s += bf2f(hv[j]) * bf2f(wvv[c][j]);
    }
    s += __shfl_xor(s, 1);
    if (kh == 0 && hr_ < mcount) out[(size_t)idx[base + hr_] * 2 + ho] = s + bh[e * 2 + ho];
  }
}

extern "C" void kernel_launch(void* const* d_in, const int* in_sizes, int n_in,
                              void* d_out, int out_size, void* d_ws, size_t ws_size,
                              hipStream_t stream) {
  const int* species = (const int*)d_in[0];
  const float* aev = (const float*)d_in[1];
  const float* W1 = (const float*)d_in[2];
  const float* b1 = (const float*)d_in[3];
  const float* W2 = (const float*)d_in[4];
  const float* b2 = (const float*)d_in[5];
  const float* W3 = (const float*)d_in[6];
  const float* b3 = (const float*)d_in[7];
  const float* Wh = (const float*)d_in[8];
  const float* bh = (const float*)d_in[9];
  float* out = (float*)d_out;

  char* p = (char*)d_ws;
  int* counts = (int*)p; p += 32;
  int* offsets = (int*)p; p += 32;
  int* cursors = (int*)p; p += 32;
  int* gstart = (int*)p; p += 32;
  int* idx = (int*)p; p += (size_t)NA * 4;
  u16* W1t = (u16*)p; p += (size_t)NS * N1 * KP1 * 2;
  u16* W2t = (u16*)p; p += (size_t)NS * N2 * N1 * 2;
  u16* W3t = (u16*)p; p += (size_t)NS * N3 * N2 * 2;
  u16* Wht = (u16*)p; p += (size_t)NS * 2 * N3 * 2;

  (void)hipMemsetAsync(counts, 0, 32, stream);
  count_kernel<<<NA / 256, 256, 0, stream>>>(species, counts);
  scan_kernel<<<1, 1, 0, stream>>>(counts, offsets, cursors, gstart);
  scatter_kernel<<<NA / 256, 256, 0, stream>>>(species, cursors, idx);

  convert_w<<<2048, 256, 0, stream>>>(W1, W1t, AEVD, N1, KP1);
  convert_w<<<1024, 256, 0, stream>>>(W2, W2t, N1, N2, N1);
  convert_w<<<512, 256, 0, stream>>>(W3, W3t, N2, N3, N2);
  convert_w<<<16, 256, 0, stream>>>(Wh, Wht, N3, 2, N3);

  int maxBlocks = NA / GR + NS;   // >= sum ceil(counts/GR)
  ani_fused<<<maxBlocks, 128, 0, stream>>>(idx, counts, offsets, gstart, aev,
                                           W1t, b1, W2t, b2, W3t, b3, Wht, bh, out);
}